// Round 4
// baseline (2642.421 us; speedup 1.0000x reference)
//
#include <hip/hip_runtime.h>

typedef unsigned short u16;
typedef unsigned int   u32;

#define ACT_NONE 0
#define ACT_RELU 1
#define ACT_TANH 2

#define E_EDGES 500000

using s8vec = __attribute__((ext_vector_type(8))) short;   // 8 bf16 (4 VGPRs) MFMA A/B frag
using f4vec = __attribute__((ext_vector_type(4))) float;   // MFMA C/D frag

__device__ __forceinline__ float bf2f(u16 u) {
  union { u32 b; float f; } v; v.b = ((u32)u) << 16; return v.f;
}
__device__ __forceinline__ u16 f2bf(float x) {
  union { float f; u32 b; } v; v.f = x;
  u32 r = v.b + 0x7fffu + ((v.b >> 16) & 1u);   // round-to-nearest-even
  return (u16)(r >> 16);
}

// ---------------------------------------------------------------------------
// transpose + cast f32->bf16 (+ optional per-row f32 scale): in[R][C] -> out[C][R]
__global__ __launch_bounds__(256) void transpose_k(
    const float* __restrict__ in, u16* __restrict__ o, int R, int C,
    const float* __restrict__ scale) {
  int i = blockIdx.x * 256 + threadIdx.x;
  if (i >= R * C) return;
  int r = i / C, c = i % C;
  float v = in[i];
  if (scale) v *= scale[r];
  o[(size_t)c * R + r] = f2bf(v);
}

// ---------------------------------------------------------------------------
// CSR build: count -> block scan -> small scan -> add/copy -> fill
__global__ __launch_bounds__(256) void count_k(
    const int* __restrict__ dst, int* __restrict__ cnt, int E) {
  int e = blockIdx.x * 256 + threadIdx.x;
  if (e < E) atomicAdd(&cnt[dst[e]], 1);
}

// per-block exclusive scan of 1024 elements (256 thr x 4), writes block total
__global__ __launch_bounds__(256) void scan_block_k(
    const int* __restrict__ in, int* __restrict__ out,
    int* __restrict__ blksum, int n) {
  __shared__ int lds[256];
  const int t = threadIdx.x;
  const int idx = blockIdx.x * 1024 + t * 4;
  int v0 = 0, v1 = 0, v2 = 0, v3 = 0;
  if (idx + 3 < n) {
    int4 v = *(const int4*)(in + idx);
    v0 = v.x; v1 = v.y; v2 = v.z; v3 = v.w;
  } else {
    if (idx + 0 < n) v0 = in[idx + 0];
    if (idx + 1 < n) v1 = in[idx + 1];
    if (idx + 2 < n) v2 = in[idx + 2];
    if (idx + 3 < n) v3 = in[idx + 3];
  }
  int s0 = v0, s1 = s0 + v1, s2 = s1 + v2, s3 = s2 + v3;  // inclusive in-thread
  lds[t] = s3;
  __syncthreads();
  for (int off = 1; off < 256; off <<= 1) {               // Hillis-Steele
    int val = (t >= off) ? lds[t - off] : 0;
    __syncthreads();
    lds[t] += val;
    __syncthreads();
  }
  int excl = t ? lds[t - 1] : 0;
  if (idx + 3 < n) {
    int4 o = {excl, excl + s0, excl + s1, excl + s2};
    *(int4*)(out + idx) = o;
  } else {
    if (idx + 0 < n) out[idx + 0] = excl;
    if (idx + 1 < n) out[idx + 1] = excl + s0;
    if (idx + 2 < n) out[idx + 2] = excl + s1;
    if (idx + 3 < n) out[idx + 3] = excl + s2;
  }
  if (t == 255) blksum[blockIdx.x] = lds[255];
}

__global__ void scan_small_k(int* __restrict__ b, int n) {
  if (threadIdx.x == 0) {
    int s = 0;
    for (int i = 0; i < n; ++i) { int t = b[i]; b[i] = s; s += t; }
  }
}

// rowptr[idx] += blkoff; cursor = rowptr; rowptr[n] = E
__global__ __launch_bounds__(256) void scan_add_k(
    int* __restrict__ rowptr, int* __restrict__ cursor,
    const int* __restrict__ blksum, int n, int E) {
  const int t = threadIdx.x;
  const int idx = blockIdx.x * 1024 + t * 4;
  int boff = blksum[blockIdx.x];
#pragma unroll
  for (int j = 0; j < 4; ++j)
    if (idx + j < n) {
      int v = rowptr[idx + j] + boff;
      rowptr[idx + j] = v;
      cursor[idx + j] = v;
    }
  if (blockIdx.x == 0 && t == 0) rowptr[n] = E;
}

__global__ __launch_bounds__(256) void fill_k(
    const int* __restrict__ src, const int* __restrict__ dst,
    int* __restrict__ cursor, int* __restrict__ esrc, int E) {
  int e = blockIdx.x * 256 + threadIdx.x;
  if (e >= E) return;
  int pos = atomicAdd(&cursor[dst[e]], 1);
  esrc[pos] = src[e];
}

// ---------------------------------------------------------------------------
// gather aggregation: aggb[d] = mean_{e: dst=d} h[src[e]]  (bf16 in/out, f32 acc)
// 16 lanes per dst row, 8 cols each
__device__ __forceinline__ void acc8(float* acc, uint4 v) {
  union { u32 b; float f; } cv;
  cv.b = v.x << 16;         acc[0] += cv.f;
  cv.b = v.x & 0xffff0000u; acc[1] += cv.f;
  cv.b = v.y << 16;         acc[2] += cv.f;
  cv.b = v.y & 0xffff0000u; acc[3] += cv.f;
  cv.b = v.z << 16;         acc[4] += cv.f;
  cv.b = v.z & 0xffff0000u; acc[5] += cv.f;
  cv.b = v.w << 16;         acc[6] += cv.f;
  cv.b = v.w & 0xffff0000u; acc[7] += cv.f;
}

__global__ __launch_bounds__(256) void gather_agg_k(
    const u16* __restrict__ h, const int* __restrict__ rowptr,
    const int* __restrict__ esrc, u16* __restrict__ aggb, int n) {
  int tid = blockIdx.x * 256 + threadIdx.x;
  int d = tid >> 4;
  if (d >= n) return;
  int part = tid & 15;
  int s0 = rowptr[d], s1 = rowptr[d + 1];
  float acc[8] = {0.f, 0.f, 0.f, 0.f, 0.f, 0.f, 0.f, 0.f};
  int i = s0;
  for (; i + 1 < s1; i += 2) {                  // 2-deep for outstanding loads
    int sa = esrc[i], sb = esrc[i + 1];
    uint4 va = *(const uint4*)(h + (size_t)sa * 128 + part * 8);
    uint4 vb = *(const uint4*)(h + (size_t)sb * 128 + part * 8);
    acc8(acc, va);
    acc8(acc, vb);
  }
  if (i < s1) {
    int sa = esrc[i];
    acc8(acc, *(const uint4*)(h + (size_t)sa * 128 + part * 8));
  }
  float rs = 1.0f / fmaxf((float)(s1 - s0), 1.0f);
  u16 o[8];
#pragma unroll
  for (int j = 0; j < 8; ++j) o[j] = f2bf(acc[j] * rs);
  *(uint4*)(aggb + (size_t)d * 128 + part * 8) = *(const uint4*)o;
}

// ---------------------------------------------------------------------------
// permuted row gather: out[i] = h[perm[i]]  (bf16 rows of 128)
__global__ __launch_bounds__(256) void permgather_k(
    const u16* __restrict__ h, const int* __restrict__ perm,
    u16* __restrict__ o, int n) {
  int tid = blockIdx.x * 256 + threadIdx.x;
  int i = tid >> 4;
  if (i >= n) return;
  int c = (tid & 15) * 8;
  int s = perm[i];
  *(uint4*)(o + (size_t)i * 128 + c) = *(const uint4*)(h + (size_t)s * 128 + c);
}

// ---------------------------------------------------------------------------
// MFMA GEMM: C[M][N] = act(A[M][K] @ B[K][N] + bias)
//  - Bt is B transposed [N][K] bf16 (global), staged in LDS with XOR-granule swizzle
//  - AMODE: 0 = bf16 A, 1 = f32 A
//  - CF32:  write f32 (else bf16)
//  - SQDIFF: don't store; accumulate sum((v - target)^2) into lossAcc
// block = 256 threads = 4 waves, 64 rows/block, wave w owns rows w*16..w*16+15
template <int K, int N, int ACT, int AMODE, bool CF32, bool SQDIFF>
__global__ __launch_bounds__(256) void gemm_k(
    const void* __restrict__ Av, int ldA,
    const u16* __restrict__ Bt, const float* __restrict__ bias,
    void* __restrict__ Cv, int ldC, int M,
    const u16* __restrict__ target, float* __restrict__ lossAcc) {
  static_assert(K % 32 == 0 && N % 16 == 0, "");
  __shared__ u16 bts[N * K];
  __shared__ float red[4];

  const int tid = threadIdx.x;
  // stage Bt -> LDS, swizzling 8-elem (16B) granules: gs = (g&~7) | ((g^n)&7)
  for (int i = tid; i < N * (K / 8); i += 256) {
    int n = i / (K / 8);
    int g = i % (K / 8);
    int gs = (g & ~7) | ((g ^ n) & 7);
    *(uint4*)(&bts[n * K + gs * 8]) = *(const uint4*)(Bt + (size_t)n * K + g * 8);
  }
  __syncthreads();

  const int wave = tid >> 6;
  const int lane = tid & 63;
  const int kgrp = lane >> 4;              // 0..3
  const int rbase = blockIdx.x * 64 + wave * 16;
  const int rowA = rbase + (lane & 15);
  const bool av = rowA < M;

  // A fragments for the whole K extent, in registers
  s8vec afr[K / 32];
  if constexpr (AMODE == 1) {
    const float* arow = (const float*)Av + (size_t)rowA * ldA;
#pragma unroll
    for (int kt = 0; kt < K / 32; ++kt) {
      s8vec fr = {0, 0, 0, 0, 0, 0, 0, 0};
      if (av) {
        const float* p = arow + kt * 32 + kgrp * 8;
#pragma unroll
        for (int j = 0; j < 8; ++j) fr[j] = (short)f2bf(p[j]);
      }
      afr[kt] = fr;
    }
  } else {
    const u16* arow = (const u16*)Av + (size_t)rowA * ldA;
#pragma unroll
    for (int kt = 0; kt < K / 32; ++kt) {
      s8vec fr = {0, 0, 0, 0, 0, 0, 0, 0};
      if (av) fr = *(const s8vec*)(arow + kt * 32 + kgrp * 8);
      afr[kt] = fr;
    }
  }

  float sqsum = 0.0f;
#pragma unroll
  for (int t = 0; t < N / 16; ++t) {
    f4vec acc = {0.f, 0.f, 0.f, 0.f};
    const int bn = t * 16 + (lane & 15);
#pragma unroll
    for (int kt = 0; kt < K / 32; ++kt) {
      int g = kt * 4 + kgrp;
      int gs = (g & ~7) | ((g ^ bn) & 7);
      s8vec bfr = *(const s8vec*)(&bts[bn * K + gs * 8]);
      acc = __builtin_amdgcn_mfma_f32_16x16x32_bf16(afr[kt], bfr, acc, 0, 0, 0);
    }
    const int col = t * 16 + (lane & 15);
    float bb = bias ? bias[col] : 0.0f;
#pragma unroll
    for (int j = 0; j < 4; ++j) {
      int r = rbase + kgrp * 4 + j;        // C/D: col=lane&15, row=(lane>>4)*4+j
      if (r < M) {
        float v = acc[j] + bb;
        if constexpr (ACT == ACT_RELU) v = fmaxf(v, 0.0f);
        if constexpr (ACT == ACT_TANH) v = tanhf(v);
        if constexpr (SQDIFF) {
          float dd = v - bf2f(target[(size_t)r * 128 + col]);
          sqsum += dd * dd;
        } else if constexpr (CF32) {
          ((float*)Cv)[(size_t)r * ldC + col] = v;
        } else {
          ((u16*)Cv)[(size_t)r * ldC + col] = f2bf(v);
        }
      }
    }
  }

  if constexpr (SQDIFF) {
#pragma unroll
    for (int off = 32; off > 0; off >>= 1) sqsum += __shfl_down(sqsum, off);
    if (lane == 0) red[wave] = sqsum;
    __syncthreads();
    if (tid == 0) atomicAdd(lossAcc, red[0] + red[1] + red[2] + red[3]);
  }
}

// ---------------------------------------------------------------------------
// orth: G_pq[i][j] += sum_n z[n][p*64+i] * z[n][q*64+j], pairs (0,1),(0,2),(1,2)
__global__ __launch_bounds__(256) void orth_k(
    const u16* __restrict__ z, int n, float* __restrict__ G3) {
  int pair = blockIdx.y;
  int p = (pair == 2) ? 1 : 0;
  int q = (pair == 0) ? 1 : 2;
  int ti = threadIdx.x >> 4, tj = threadIdx.x & 15;
  float acc[4][4];
#pragma unroll
  for (int i = 0; i < 4; ++i)
#pragma unroll
    for (int j = 0; j < 4; ++j) acc[i][j] = 0.f;
  int r0 = blockIdx.x * 1024;
  int r1 = min(n, r0 + 1024);
  for (int r = r0; r < r1; ++r) {
    const u16* zr = z + (size_t)r * 192;
    ushort4 a = *(const ushort4*)(zr + p * 64 + ti * 4);
    ushort4 b = *(const ushort4*)(zr + q * 64 + tj * 4);
    float zi[4] = {bf2f(a.x), bf2f(a.y), bf2f(a.z), bf2f(a.w)};
    float zj[4] = {bf2f(b.x), bf2f(b.y), bf2f(b.z), bf2f(b.w)};
#pragma unroll
    for (int i = 0; i < 4; ++i)
#pragma unroll
      for (int j = 0; j < 4; ++j) acc[i][j] += zi[i] * zj[j];
  }
  float* g = G3 + pair * 4096;
#pragma unroll
  for (int i = 0; i < 4; ++i)
#pragma unroll
    for (int j = 0; j < 4; ++j)
      atomicAdd(&g[(ti * 4 + i) * 64 + (tj * 4 + j)], acc[i][j]);
}

// ---------------------------------------------------------------------------
__global__ __launch_bounds__(256) void loss_k(
    const float* __restrict__ G, const float* __restrict__ RE,
    float* __restrict__ out) {
  float s = 0.f;
  for (int i = threadIdx.x; i < 2 * 3 * 4096; i += 256) { float g = G[i]; s += g * g; }
#pragma unroll
  for (int off = 32; off > 0; off >>= 1) s += __shfl_down(s, off);
  __shared__ float red[4];
  int wave = threadIdx.x >> 6, lane = threadIdx.x & 63;
  if (lane == 0) red[wave] = s;
  __syncthreads();
  if (threadIdx.x == 0) {
    float orth = (red[0] + red[1] + red[2] + red[3]) / 4096.0f;
    float loss = orth + RE[0] / (50000.0f * 128.0f) + RE[1] / (80000.0f * 128.0f);
    out[0] = loss;
  }
}

// ---------------------------------------------------------------------------
struct HopDesc { int et; int src_tf; int n_dst; int out_p; };  // src_tf: -1 = H buffer

static const int COUNTS_H[3] = {50000, 80000, 10000};
static const int OFFS_H[3]   = {0, 50000, 130000};
static const int GRP_H[5]    = {2, 1, 1, 2, 1};                // GCN_GROUP

static const HopDesc HOPS_U[7] = {
  {0, 0, 80000, -1}, {1, -1, 50000, 0},
  {0, 0, 80000, -1}, {2, -1, 10000, -1}, {3, -1, 80000, -1}, {1, -1, 50000, 1},
  {4, 0, 50000, 2}};
static const HopDesc HOPS_I[7] = {
  {1, 1, 50000, -1}, {0, -1, 80000, 0},
  {2, 1, 10000, -1}, {3, -1, 80000, 1},
  {1, 1, 50000, -1}, {4, -1, 50000, -1}, {0, -1, 80000, 2}};

extern "C" void kernel_launch(void* const* d_in, const int* in_sizes, int n_in,
                              void* d_out, int out_size, void* d_ws, size_t ws_size,
                              hipStream_t stream) {
  (void)in_sizes; (void)n_in; (void)out_size; (void)ws_size;

  const float* features = (const float*)d_in[0];
  const int* e_user   = (const int*)d_in[1];
  const int* e_item   = (const int*)d_in[2];
  const int* perm_u   = (const int*)d_in[3];
  const int* perm_i   = (const int*)d_in[4];
  const float* W_type = (const float*)d_in[5];
  const float* b_type = (const float*)d_in[6];
  const float* comp   = (const float*)d_in[7];
  const float* W_gcn  = (const float*)d_in[8];
  const float* b_gcn  = (const float*)d_in[9];
  const float* fc[2]  = {(const float*)d_in[10], (const float*)d_in[14]};
  const float* fcr[2] = {(const float*)d_in[11], (const float*)d_in[15]};
  const float* V[2]   = {(const float*)d_in[12], (const float*)d_in[16]};
  const float* Vr[2]  = {(const float*)d_in[13], (const float*)d_in[17]};
  float* out = (float*)d_out;

  char* base = (char*)d_ws;
  size_t off = 0;
  auto alloc = [&](size_t b) -> void* {
    void* p = base + off;
    off = (off + b + 255) & ~(size_t)255;
    return p;
  };
  u16*  TF   = (u16*) alloc(140000ull * 128 * 2);
  u16*  H    = (u16*) alloc(80000ull * 128 * 2);
  u16*  AGGB = (u16*) alloc(80000ull * 128 * 2);
  u16*  OUTS = (u16*) alloc(3ull * 80000 * 128 * 2);
  u16*  Z    = (u16*) alloc(80000ull * 192 * 2);
  u16*  ZREC = (u16*) alloc(80000ull * 192 * 2);
  float* G   = (float*)alloc((2 * 3 * 4096 + 2) * 4);
  float* RE  = G + 2 * 3 * 4096;
  int* CNT    = (int*)alloc(80000ull * 4);
  int* ROWPTR = (int*)alloc(80001ull * 4);
  int* CURSOR = (int*)alloc(80000ull * 4);
  int* ESRC   = (int*)alloc((size_t)E_EDGES * 4);
  int* BLKSUM = (int*)alloc(128ull * 4);
  u16* WT_TYPE = (u16*)alloc(3ull * 128 * 256 * 2);
  u16* BT_HOP  = (u16*)alloc(5ull * 128 * 128 * 2);
  u16* FCT     = (u16*)alloc(6ull * 64 * 128 * 2);
  u16* VT      = (u16*)alloc(2ull * 128 * 192 * 2);
  u16* VRT     = (u16*)alloc(2ull * 192 * 128 * 2);
  u16* FCRT    = (u16*)alloc(6ull * 128 * 64 * 2);

  auto tgrid = [](int n) { return dim3((unsigned)((n + 255) / 256)); };
  auto ggrid = [](int M) { return dim3((unsigned)((M + 63) / 64)); };
  const dim3 egrid((E_EDGES + 255) / 256);

  // ---- weight prep: transposed (and comp-folded) bf16 copies -------------
  for (int t = 0; t < 3; ++t)
    transpose_k<<<tgrid(256 * 128), 256, 0, stream>>>(
        W_type + (size_t)t * 256 * 128, WT_TYPE + (size_t)t * 128 * 256, 256, 128, nullptr);
  for (int et = 0; et < 5; ++et)
    transpose_k<<<tgrid(128 * 128), 256, 0, stream>>>(
        W_gcn + (size_t)GRP_H[et] * 128 * 128, BT_HOP + (size_t)et * 128 * 128, 128, 128,
        comp + (size_t)et * 128);
  for (int L = 0; L < 2; ++L) {
    for (int p = 0; p < 3; ++p) {
      transpose_k<<<tgrid(128 * 64), 256, 0, stream>>>(
          fc[L] + (size_t)p * 128 * 64, FCT + (size_t)(L * 3 + p) * 64 * 128, 128, 64, nullptr);
      transpose_k<<<tgrid(64 * 128), 256, 0, stream>>>(
          fcr[L] + (size_t)p * 64 * 128, FCRT + (size_t)(L * 3 + p) * 128 * 64, 64, 128, nullptr);
    }
    transpose_k<<<tgrid(192 * 128), 256, 0, stream>>>(V[L], VT + (size_t)L * 128 * 192, 192, 128, nullptr);
    transpose_k<<<tgrid(128 * 192), 256, 0, stream>>>(Vr[L], VRT + (size_t)L * 192 * 128, 128, 192, nullptr);
  }
  hipMemsetAsync(G, 0, (2 * 3 * 4096 + 2) * 4, stream);

  // ---- NodeTransform: TF[t] = relu(features_t @ W_type[t] + b_type[t]) ---
  for (int t = 0; t < 3; ++t)
    gemm_k<256, 128, ACT_RELU, 1, false, false><<<ggrid(COUNTS_H[t]), 256, 0, stream>>>(
        features + (size_t)OFFS_H[t] * 256, 256, WT_TYPE + (size_t)t * 128 * 256,
        b_type + (size_t)t * 128, TF + (size_t)OFFS_H[t] * 128, 128, COUNTS_H[t],
        nullptr, nullptr);

  // ---- two layers ---------------------------------------------------------
  for (int L = 0; L < 2; ++L) {
    const HopDesc* hops = L ? HOPS_I : HOPS_U;
    const int* edges = L ? e_item : e_user;
    const int* perm  = L ? perm_i : perm_u;
    const int  nL    = L ? 80000 : 50000;

    for (int k = 0; k < 7; ++k) {
      const HopDesc hd = hops[k];
      const u16* hsrc = (hd.src_tf >= 0) ? (TF + (size_t)OFFS_H[hd.src_tf] * 128) : H;
      const int* src = edges + (size_t)k * 2 * E_EDGES;
      const int* dst = src + E_EDGES;
      const int n = hd.n_dst;
      const int nblk = (n + 1023) / 1024;

      // CSR by dst
      hipMemsetAsync(CNT, 0, (size_t)n * 4, stream);
      count_k<<<egrid, 256, 0, stream>>>(dst, CNT, E_EDGES);
      scan_block_k<<<dim3(nblk), 256, 0, stream>>>(CNT, ROWPTR, BLKSUM, n);
      scan_small_k<<<dim3(1), 64, 0, stream>>>(BLKSUM, nblk);
      scan_add_k<<<dim3(nblk), 256, 0, stream>>>(ROWPTR, CURSOR, BLKSUM, n, E_EDGES);
      fill_k<<<egrid, 256, 0, stream>>>(src, dst, CURSOR, ESRC, E_EDGES);

      // mean-aggregate into bf16
      gather_agg_k<<<dim3((n * 16 + 255) / 256), 256, 0, stream>>>(
          hsrc, ROWPTR, ESRC, AGGB, n);

      // h = agg @ (diag(comp)*W_gcn[g]) + b_gcn[g]
      gemm_k<128, 128, ACT_NONE, 0, false, false><<<ggrid(n), 256, 0, stream>>>(
          AGGB, 128, BT_HOP + (size_t)hd.et * 128 * 128, b_gcn + (size_t)GRP_H[hd.et] * 128,
          H, 128, n, nullptr, nullptr);
      if (hd.out_p >= 0)
        permgather_k<<<dim3((nL * 16 + 255) / 256), 256, 0, stream>>>(
            H, perm, OUTS + (size_t)hd.out_p * 80000 * 128, nL);
    }

    // fusion
    for (int p = 0; p < 3; ++p)
      gemm_k<128, 64, ACT_TANH, 0, false, false><<<ggrid(nL), 256, 0, stream>>>(
          OUTS + (size_t)p * 80000 * 128, 128, FCT + (size_t)(L * 3 + p) * 64 * 128, nullptr,
          Z + p * 64, 192, nL, nullptr, nullptr);
    float* fused = out + (L ? 6400000 : 0);
    gemm_k<192, 128, ACT_NONE, 0, true, false><<<ggrid(nL), 256, 0, stream>>>(
        Z, 192, VT + (size_t)L * 128 * 192, nullptr, fused, 128, nL, nullptr, nullptr);
    gemm_k<128, 192, ACT_NONE, 1, false, false><<<ggrid(nL), 256, 0, stream>>>(
        fused, 128, VRT + (size_t)L * 192 * 128, nullptr, ZREC, 192, nL, nullptr, nullptr);
    for (int p = 0; p < 3; ++p)
      gemm_k<64, 128, ACT_NONE, 0, false, true><<<ggrid(nL), 256, 0, stream>>>(
          ZREC + p * 64, 192, FCRT + (size_t)(L * 3 + p) * 128 * 64, nullptr,
          nullptr, 128, nL, OUTS + (size_t)p * 80000 * 128, RE + L);
    orth_k<<<dim3((nL + 1023) / 1024, 3), 256, 0, stream>>>(Z, nL, G + (size_t)L * 3 * 4096);
  }

  loss_k<<<1, 256, 0, stream>>>(G, RE, out + 16640000);
}

// Round 5
// 1958.704 us; speedup vs baseline: 1.3491x; 1.3491x over previous
//
#include <hip/hip_runtime.h>

typedef unsigned short u16;
typedef unsigned int   u32;

#define ACT_NONE 0
#define ACT_RELU 1
#define ACT_TANH 2

#define E_EDGES 500000

using s8vec = __attribute__((ext_vector_type(8))) short;   // 8 bf16 (4 VGPRs) MFMA A/B frag
using f4vec = __attribute__((ext_vector_type(4))) float;   // MFMA C/D frag

__device__ __forceinline__ float bf2f(u16 u) {
  union { u32 b; float f; } v; v.b = ((u32)u) << 16; return v.f;
}
__device__ __forceinline__ u16 f2bf(float x) {
  union { float f; u32 b; } v; v.f = x;
  u32 r = v.b + 0x7fffu + ((v.b >> 16) & 1u);   // round-to-nearest-even
  return (u16)(r >> 16);
}

// ---------------------------------------------------------------------------
// transpose + cast f32->bf16 (+ optional per-row f32 scale): in[R][C] -> out[C][R]
__global__ __launch_bounds__(256) void transpose_k(
    const float* __restrict__ in, u16* __restrict__ o, int R, int C,
    const float* __restrict__ scale) {
  int i = blockIdx.x * 256 + threadIdx.x;
  if (i >= R * C) return;
  int r = i / C, c = i % C;
  float v = in[i];
  if (scale) v *= scale[r];
  o[(size_t)c * R + r] = f2bf(v);
}

// ---------------------------------------------------------------------------
// Batched CSR build over 7 hops of one layer (blockIdx.y = hop)
struct CsrParams { int n[7]; int nblk[7]; };

#define RP_STRIDE 80004   // rowptr/cursor/cnt per-hop stride (ints, 16B-aligned)

__global__ __launch_bounds__(256) void count_b_k(
    const int* __restrict__ edges, CsrParams cp, int* __restrict__ cnt) {
  int hop = blockIdx.y;
  int e = blockIdx.x * 256 + threadIdx.x;
  if (e >= E_EDGES) return;
  int d = edges[(size_t)(hop * 2 + 1) * E_EDGES + e];
  atomicAdd(&cnt[hop * RP_STRIDE + d], 1);
}

// per-block exclusive scan of 1024 elements (256 thr x 4), writes block total
__global__ __launch_bounds__(256) void scan_block_b_k(
    const int* __restrict__ cntb, int* __restrict__ rowptrb,
    int* __restrict__ blksumb, CsrParams cp) {
  __shared__ int lds[256];
  const int hop = blockIdx.y;
  const int n = cp.n[hop];
  if (blockIdx.x * 1024 >= n) return;
  const int* in = cntb + hop * RP_STRIDE;
  int* out = rowptrb + hop * RP_STRIDE;
  const int t = threadIdx.x;
  const int idx = blockIdx.x * 1024 + t * 4;
  int v0 = 0, v1 = 0, v2 = 0, v3 = 0;
  if (idx + 3 < n) {
    int4 v = *(const int4*)(in + idx);
    v0 = v.x; v1 = v.y; v2 = v.z; v3 = v.w;
  } else {
    if (idx + 0 < n) v0 = in[idx + 0];
    if (idx + 1 < n) v1 = in[idx + 1];
    if (idx + 2 < n) v2 = in[idx + 2];
    if (idx + 3 < n) v3 = in[idx + 3];
  }
  int s0 = v0, s1 = s0 + v1, s2 = s1 + v2, s3 = s2 + v3;  // inclusive in-thread
  lds[t] = s3;
  __syncthreads();
  for (int off = 1; off < 256; off <<= 1) {               // Hillis-Steele
    int val = (t >= off) ? lds[t - off] : 0;
    __syncthreads();
    lds[t] += val;
    __syncthreads();
  }
  int excl = t ? lds[t - 1] : 0;
  if (idx + 3 < n) {
    int4 o = {excl, excl + s0, excl + s1, excl + s2};
    *(int4*)(out + idx) = o;
  } else {
    if (idx + 0 < n) out[idx + 0] = excl;
    if (idx + 1 < n) out[idx + 1] = excl + s0;
    if (idx + 2 < n) out[idx + 2] = excl + s1;
    if (idx + 3 < n) out[idx + 3] = excl + s2;
  }
  if (t == 255) blksumb[hop * 128 + blockIdx.x] = lds[255];
}

__global__ void scan_small_b_k(int* __restrict__ blksumb, CsrParams cp) {
  int hop = blockIdx.x;
  if (threadIdx.x == 0) {
    int* b = blksumb + hop * 128;
    int s = 0;
    int nb = cp.nblk[hop];
    for (int i = 0; i < nb; ++i) { int t = b[i]; b[i] = s; s += t; }
  }
}

// rowptr[idx] += blkoff; cursor = rowptr; rowptr[n] = E
__global__ __launch_bounds__(256) void scan_add_b_k(
    int* __restrict__ rowptrb, int* __restrict__ cursorb,
    const int* __restrict__ blksumb, CsrParams cp) {
  const int hop = blockIdx.y;
  const int n = cp.n[hop];
  if (blockIdx.x * 1024 >= n) return;
  int* rowptr = rowptrb + hop * RP_STRIDE;
  int* cursor = cursorb + hop * RP_STRIDE;
  const int t = threadIdx.x;
  const int idx = blockIdx.x * 1024 + t * 4;
  int boff = blksumb[hop * 128 + blockIdx.x];
#pragma unroll
  for (int j = 0; j < 4; ++j)
    if (idx + j < n) {
      int v = rowptr[idx + j] + boff;
      rowptr[idx + j] = v;
      cursor[idx + j] = v;
    }
  if (blockIdx.x == 0 && t == 0) rowptr[n] = E_EDGES;
}

__global__ __launch_bounds__(256) void fill_b_k(
    const int* __restrict__ edges, int* __restrict__ cursorb,
    int* __restrict__ esrcb, CsrParams cp) {
  int hop = blockIdx.y;
  int e = blockIdx.x * 256 + threadIdx.x;
  if (e >= E_EDGES) return;
  int s = edges[(size_t)(hop * 2) * E_EDGES + e];
  int d = edges[(size_t)(hop * 2 + 1) * E_EDGES + e];
  int pos = atomicAdd(&cursorb[hop * RP_STRIDE + d], 1);
  esrcb[(size_t)hop * E_EDGES + pos] = s;
}

// ---------------------------------------------------------------------------
// gather aggregation: aggb[d] = mean_{e: dst=d} h[src[e]]  (bf16 in/out, f32 acc)
// 16 lanes per dst row, 8 cols each
__device__ __forceinline__ void acc8(float* acc, uint4 v) {
  union { u32 b; float f; } cv;
  cv.b = v.x << 16;         acc[0] += cv.f;
  cv.b = v.x & 0xffff0000u; acc[1] += cv.f;
  cv.b = v.y << 16;         acc[2] += cv.f;
  cv.b = v.y & 0xffff0000u; acc[3] += cv.f;
  cv.b = v.z << 16;         acc[4] += cv.f;
  cv.b = v.z & 0xffff0000u; acc[5] += cv.f;
  cv.b = v.w << 16;         acc[6] += cv.f;
  cv.b = v.w & 0xffff0000u; acc[7] += cv.f;
}

__global__ __launch_bounds__(256) void gather_agg_k(
    const u16* __restrict__ h, const int* __restrict__ rowptr,
    const int* __restrict__ esrc, u16* __restrict__ aggb, int n) {
  int tid = blockIdx.x * 256 + threadIdx.x;
  int d = tid >> 4;
  if (d >= n) return;
  int part = tid & 15;
  int s0 = rowptr[d], s1 = rowptr[d + 1];
  float acc[8] = {0.f, 0.f, 0.f, 0.f, 0.f, 0.f, 0.f, 0.f};
  int i = s0;
  for (; i + 1 < s1; i += 2) {                  // 2-deep for outstanding loads
    int sa = esrc[i], sb = esrc[i + 1];
    uint4 va = *(const uint4*)(h + (size_t)sa * 128 + part * 8);
    uint4 vb = *(const uint4*)(h + (size_t)sb * 128 + part * 8);
    acc8(acc, va);
    acc8(acc, vb);
  }
  if (i < s1) {
    int sa = esrc[i];
    acc8(acc, *(const uint4*)(h + (size_t)sa * 128 + part * 8));
  }
  float rs = 1.0f / fmaxf((float)(s1 - s0), 1.0f);
  u16 o[8];
#pragma unroll
  for (int j = 0; j < 8; ++j) o[j] = f2bf(acc[j] * rs);
  *(uint4*)(aggb + (size_t)d * 128 + part * 8) = *(const uint4*)o;
}

// ---------------------------------------------------------------------------
// permuted row gather: out[i] = h[perm[i]]  (bf16 rows of 128)
__global__ __launch_bounds__(256) void permgather_k(
    const u16* __restrict__ h, const int* __restrict__ perm,
    u16* __restrict__ o, int n) {
  int tid = blockIdx.x * 256 + threadIdx.x;
  int i = tid >> 4;
  if (i >= n) return;
  int c = (tid & 15) * 8;
  int s = perm[i];
  *(uint4*)(o + (size_t)i * 128 + c) = *(const uint4*)(h + (size_t)s * 128 + c);
}

// ---------------------------------------------------------------------------
// MFMA GEMM: C[M][N] = act(A[M][K] @ B[K][N] + bias)
//  - Bt is B transposed [N][K] bf16 (global), staged in LDS with XOR-granule swizzle
//  - AMODE: 0 = bf16 A, 1 = f32 A
//  - CF32:  write f32 (else bf16)
//  - CTR:   additionally write C transposed (bf16) to Ct[col][row], ld=ldCt
//  - SQDIFF: don't store; accumulate sum((v - target)^2) into lossAcc
// block = 256 threads = 4 waves, 64 rows/block, wave w owns rows w*16..w*16+15
template <int K, int N, int ACT, int AMODE, bool CF32, bool SQDIFF, bool CTR = false>
__global__ __launch_bounds__(256) void gemm_k(
    const void* __restrict__ Av, int ldA,
    const u16* __restrict__ Bt, const float* __restrict__ bias,
    void* __restrict__ Cv, int ldC, int M,
    const u16* __restrict__ target, float* __restrict__ lossAcc,
    u16* __restrict__ Ct = nullptr, int ldCt = 0) {
  static_assert(K % 32 == 0 && N % 16 == 0, "");
  __shared__ u16 bts[N * K];
  __shared__ float red[4];

  const int tid = threadIdx.x;
  // stage Bt -> LDS, swizzling 8-elem (16B) granules: gs = (g&~7) | ((g^n)&7)
  for (int i = tid; i < N * (K / 8); i += 256) {
    int n = i / (K / 8);
    int g = i % (K / 8);
    int gs = (g & ~7) | ((g ^ n) & 7);
    *(uint4*)(&bts[n * K + gs * 8]) = *(const uint4*)(Bt + (size_t)n * K + g * 8);
  }
  __syncthreads();

  const int wave = tid >> 6;
  const int lane = tid & 63;
  const int kgrp = lane >> 4;              // 0..3
  const int rbase = blockIdx.x * 64 + wave * 16;
  const int rowA = rbase + (lane & 15);
  const bool av = rowA < M;

  // A fragments for the whole K extent, in registers
  s8vec afr[K / 32];
  if constexpr (AMODE == 1) {
    const float* arow = (const float*)Av + (size_t)rowA * ldA;
#pragma unroll
    for (int kt = 0; kt < K / 32; ++kt) {
      s8vec fr = {0, 0, 0, 0, 0, 0, 0, 0};
      if (av) {
        const float* p = arow + kt * 32 + kgrp * 8;
#pragma unroll
        for (int j = 0; j < 8; ++j) fr[j] = (short)f2bf(p[j]);
      }
      afr[kt] = fr;
    }
  } else {
    const u16* arow = (const u16*)Av + (size_t)rowA * ldA;
#pragma unroll
    for (int kt = 0; kt < K / 32; ++kt) {
      s8vec fr = {0, 0, 0, 0, 0, 0, 0, 0};
      if (av) fr = *(const s8vec*)(arow + kt * 32 + kgrp * 8);
      afr[kt] = fr;
    }
  }

  float sqsum = 0.0f;
#pragma unroll
  for (int t = 0; t < N / 16; ++t) {
    f4vec acc = {0.f, 0.f, 0.f, 0.f};
    const int bn = t * 16 + (lane & 15);
#pragma unroll
    for (int kt = 0; kt < K / 32; ++kt) {
      int g = kt * 4 + kgrp;
      int gs = (g & ~7) | ((g ^ bn) & 7);
      s8vec bfr = *(const s8vec*)(&bts[bn * K + gs * 8]);
      acc = __builtin_amdgcn_mfma_f32_16x16x32_bf16(afr[kt], bfr, acc, 0, 0, 0);
    }
    const int col = t * 16 + (lane & 15);
    float bb = bias ? bias[col] : 0.0f;
#pragma unroll
    for (int j = 0; j < 4; ++j) {
      int r = rbase + kgrp * 4 + j;        // C/D: col=lane&15, row=(lane>>4)*4+j
      if (r < M) {
        float v = acc[j] + bb;
        if constexpr (ACT == ACT_RELU) v = fmaxf(v, 0.0f);
        if constexpr (ACT == ACT_TANH) v = tanhf(v);
        if constexpr (SQDIFF) {
          float dd = v - bf2f(target[(size_t)r * 128 + col]);
          sqsum += dd * dd;
        } else if constexpr (CF32) {
          ((float*)Cv)[(size_t)r * ldC + col] = v;
        } else {
          ((u16*)Cv)[(size_t)r * ldC + col] = f2bf(v);
        }
        if constexpr (CTR) {
          Ct[(size_t)col * ldCt + r] = f2bf(v);
        }
      }
    }
  }

  if constexpr (SQDIFF) {
#pragma unroll
    for (int off = 32; off > 0; off >>= 1) sqsum += __shfl_down(sqsum, off);
    if (lane == 0) red[wave] = sqsum;
    __syncthreads();
    if (tid == 0) atomicAdd(lossAcc, red[0] + red[1] + red[2] + red[3]);
  }
}

// ---------------------------------------------------------------------------
// Gram via MFMA: for pair (p,q), G_pair[m][n] += sum_r ZT[p*64+m][r]*ZT[q*64+n][r]
// grid = (NKB, 3); block = 4 waves; wave w owns G rows [w*16, w*16+16)
#define GRAM_NKB 40
__global__ __launch_bounds__(256) void gram_k(
    const u16* __restrict__ zt, int NP, float* __restrict__ G3) {
  const int pair = blockIdx.y;
  const int p = (pair == 2) ? 1 : 0;
  const int q = (pair == 0) ? 1 : 2;
  const int wave = threadIdx.x >> 6;
  const int lane = threadIdx.x & 63;
  const int kgrp = lane >> 4, lid = lane & 15;

  const int KC = (((NP + GRAM_NKB - 1) / GRAM_NKB) + 31) & ~31;
  const int kbeg = blockIdx.x * KC;
  const int kend = min(NP, kbeg + KC);

  const u16* arow = zt + (size_t)(p * 64 + wave * 16 + lid) * NP;
  const u16* brow0 = zt + (size_t)(q * 64 + 0 * 16 + lid) * NP;
  const u16* brow1 = zt + (size_t)(q * 64 + 1 * 16 + lid) * NP;
  const u16* brow2 = zt + (size_t)(q * 64 + 2 * 16 + lid) * NP;
  const u16* brow3 = zt + (size_t)(q * 64 + 3 * 16 + lid) * NP;

  f4vec acc0 = {0.f, 0.f, 0.f, 0.f};
  f4vec acc1 = {0.f, 0.f, 0.f, 0.f};
  f4vec acc2 = {0.f, 0.f, 0.f, 0.f};
  f4vec acc3 = {0.f, 0.f, 0.f, 0.f};

  for (int k0 = kbeg; k0 < kend; k0 += 32) {
    const int ko = k0 + kgrp * 8;
    s8vec af = *(const s8vec*)(arow + ko);
    s8vec b0 = *(const s8vec*)(brow0 + ko);
    s8vec b1 = *(const s8vec*)(brow1 + ko);
    s8vec b2 = *(const s8vec*)(brow2 + ko);
    s8vec b3 = *(const s8vec*)(brow3 + ko);
    acc0 = __builtin_amdgcn_mfma_f32_16x16x32_bf16(af, b0, acc0, 0, 0, 0);
    acc1 = __builtin_amdgcn_mfma_f32_16x16x32_bf16(af, b1, acc1, 0, 0, 0);
    acc2 = __builtin_amdgcn_mfma_f32_16x16x32_bf16(af, b2, acc2, 0, 0, 0);
    acc3 = __builtin_amdgcn_mfma_f32_16x16x32_bf16(af, b3, acc3, 0, 0, 0);
  }

  float* g = G3 + (size_t)pair * 4096;
  const int mrow = wave * 16 + kgrp * 4;
#pragma unroll
  for (int j = 0; j < 4; ++j) {
    atomicAdd(&g[(mrow + j) * 64 + 0 * 16 + lid], acc0[j]);
    atomicAdd(&g[(mrow + j) * 64 + 1 * 16 + lid], acc1[j]);
    atomicAdd(&g[(mrow + j) * 64 + 2 * 16 + lid], acc2[j]);
    atomicAdd(&g[(mrow + j) * 64 + 3 * 16 + lid], acc3[j]);
  }
}

// ---------------------------------------------------------------------------
__global__ __launch_bounds__(256) void loss_k(
    const float* __restrict__ G, const float* __restrict__ RE,
    float* __restrict__ out) {
  float s = 0.f;
  for (int i = threadIdx.x; i < 2 * 3 * 4096; i += 256) { float g = G[i]; s += g * g; }
#pragma unroll
  for (int off = 32; off > 0; off >>= 1) s += __shfl_down(s, off);
  __shared__ float red[4];
  int wave = threadIdx.x >> 6, lane = threadIdx.x & 63;
  if (lane == 0) red[wave] = s;
  __syncthreads();
  if (threadIdx.x == 0) {
    float orth = (red[0] + red[1] + red[2] + red[3]) / 4096.0f;
    float loss = orth + RE[0] / (50000.0f * 128.0f) + RE[1] / (80000.0f * 128.0f);
    out[0] = loss;
  }
}

// ---------------------------------------------------------------------------
struct HopDesc { int et; int src_tf; int n_dst; int out_p; };  // src_tf: -1 = H buffer

static const int COUNTS_H[3] = {50000, 80000, 10000};
static const int OFFS_H[3]   = {0, 50000, 130000};
static const int GRP_H[5]    = {2, 1, 1, 2, 1};                // GCN_GROUP

static const HopDesc HOPS_U[7] = {
  {0, 0, 80000, -1}, {1, -1, 50000, 0},
  {0, 0, 80000, -1}, {2, -1, 10000, -1}, {3, -1, 80000, -1}, {1, -1, 50000, 1},
  {4, 0, 50000, 2}};
static const HopDesc HOPS_I[7] = {
  {1, 1, 50000, -1}, {0, -1, 80000, 0},
  {2, 1, 10000, -1}, {3, -1, 80000, 1},
  {1, 1, 50000, -1}, {4, -1, 50000, -1}, {0, -1, 80000, 2}};

extern "C" void kernel_launch(void* const* d_in, const int* in_sizes, int n_in,
                              void* d_out, int out_size, void* d_ws, size_t ws_size,
                              hipStream_t stream) {
  (void)in_sizes; (void)n_in; (void)out_size; (void)ws_size;

  const float* features = (const float*)d_in[0];
  const int* e_user   = (const int*)d_in[1];
  const int* e_item   = (const int*)d_in[2];
  const int* perm_u   = (const int*)d_in[3];
  const int* perm_i   = (const int*)d_in[4];
  const float* W_type = (const float*)d_in[5];
  const float* b_type = (const float*)d_in[6];
  const float* comp   = (const float*)d_in[7];
  const float* W_gcn  = (const float*)d_in[8];
  const float* b_gcn  = (const float*)d_in[9];
  const float* fc[2]  = {(const float*)d_in[10], (const float*)d_in[14]};
  const float* fcr[2] = {(const float*)d_in[11], (const float*)d_in[15]};
  const float* V[2]   = {(const float*)d_in[12], (const float*)d_in[16]};
  const float* Vr[2]  = {(const float*)d_in[13], (const float*)d_in[17]};
  float* out = (float*)d_out;

  char* base = (char*)d_ws;
  size_t off = 0;
  auto alloc = [&](size_t b) -> void* {
    void* p = base + off;
    off = (off + b + 255) & ~(size_t)255;
    return p;
  };
  u16*  TF   = (u16*) alloc(140000ull * 128 * 2);
  u16*  H    = (u16*) alloc(80000ull * 128 * 2);
  u16*  AGGB = (u16*) alloc(80000ull * 128 * 2);
  u16*  OUTS = (u16*) alloc(3ull * 80000 * 128 * 2);
  u16*  Z    = (u16*) alloc(80000ull * 192 * 2);
  u16*  ZREC = (u16*) alloc(80000ull * 192 * 2);
  u16*  ZT   = (u16*) alloc(192ull * 80032 * 2);
  float* G   = (float*)alloc((2 * 3 * 4096 + 2) * 4);
  float* RE  = G + 2 * 3 * 4096;
  int* CNT7    = (int*)alloc(7ull * RP_STRIDE * 4);
  int* ROWPTR7 = (int*)alloc(7ull * RP_STRIDE * 4);
  int* CURSOR7 = (int*)alloc(7ull * RP_STRIDE * 4);
  int* ESRC7   = (int*)alloc(7ull * E_EDGES * 4);
  int* BLKSUM7 = (int*)alloc(7ull * 128 * 4);
  u16* WT_TYPE = (u16*)alloc(3ull * 128 * 256 * 2);
  u16* BT_HOP  = (u16*)alloc(5ull * 128 * 128 * 2);
  u16* FCT     = (u16*)alloc(6ull * 64 * 128 * 2);
  u16* VT      = (u16*)alloc(2ull * 128 * 192 * 2);
  u16* VRT     = (u16*)alloc(2ull * 192 * 128 * 2);
  u16* FCRT    = (u16*)alloc(6ull * 128 * 64 * 2);

  auto tgrid = [](int n) { return dim3((unsigned)((n + 255) / 256)); };
  auto ggrid = [](int M) { return dim3((unsigned)((M + 63) / 64)); };
  const dim3 egrid7((E_EDGES + 255) / 256, 7);

  // ---- weight prep: transposed (and comp-folded) bf16 copies -------------
  for (int t = 0; t < 3; ++t)
    transpose_k<<<tgrid(256 * 128), 256, 0, stream>>>(
        W_type + (size_t)t * 256 * 128, WT_TYPE + (size_t)t * 128 * 256, 256, 128, nullptr);
  for (int et = 0; et < 5; ++et)
    transpose_k<<<tgrid(128 * 128), 256, 0, stream>>>(
        W_gcn + (size_t)GRP_H[et] * 128 * 128, BT_HOP + (size_t)et * 128 * 128, 128, 128,
        comp + (size_t)et * 128);
  for (int L = 0; L < 2; ++L) {
    for (int p = 0; p < 3; ++p) {
      transpose_k<<<tgrid(128 * 64), 256, 0, stream>>>(
          fc[L] + (size_t)p * 128 * 64, FCT + (size_t)(L * 3 + p) * 64 * 128, 128, 64, nullptr);
      transpose_k<<<tgrid(64 * 128), 256, 0, stream>>>(
          fcr[L] + (size_t)p * 64 * 128, FCRT + (size_t)(L * 3 + p) * 128 * 64, 64, 128, nullptr);
    }
    transpose_k<<<tgrid(192 * 128), 256, 0, stream>>>(V[L], VT + (size_t)L * 128 * 192, 192, 128, nullptr);
    transpose_k<<<tgrid(128 * 192), 256, 0, stream>>>(Vr[L], VRT + (size_t)L * 192 * 128, 128, 192, nullptr);
  }
  hipMemsetAsync(G, 0, (2 * 3 * 4096 + 2) * 4, stream);

  // ---- NodeTransform: TF[t] = relu(features_t @ W_type[t] + b_type[t]) ---
  for (int t = 0; t < 3; ++t)
    gemm_k<256, 128, ACT_RELU, 1, false, false><<<ggrid(COUNTS_H[t]), 256, 0, stream>>>(
        features + (size_t)OFFS_H[t] * 256, 256, WT_TYPE + (size_t)t * 128 * 256,
        b_type + (size_t)t * 128, TF + (size_t)OFFS_H[t] * 128, 128, COUNTS_H[t],
        nullptr, nullptr);

  // ---- two layers ---------------------------------------------------------
  for (int L = 0; L < 2; ++L) {
    const HopDesc* hops = L ? HOPS_I : HOPS_U;
    const int* edges = L ? e_item : e_user;
    const int* perm  = L ? perm_i : perm_u;
    const int  nL    = L ? 80000 : 50000;
    const int  NP    = (nL + 31) & ~31;           // K-padded node count for ZT

    // batched CSR build for all 7 hops of this layer
    CsrParams cp;
    for (int k = 0; k < 7; ++k) {
      cp.n[k] = hops[k].n_dst;
      cp.nblk[k] = (hops[k].n_dst + 1023) / 1024;
    }
    hipMemsetAsync(CNT7, 0, 7ull * RP_STRIDE * 4, stream);
    count_b_k<<<egrid7, 256, 0, stream>>>(edges, cp, CNT7);
    scan_block_b_k<<<dim3(79, 7), 256, 0, stream>>>(CNT7, ROWPTR7, BLKSUM7, cp);
    scan_small_b_k<<<dim3(7), 64, 0, stream>>>(BLKSUM7, cp);
    scan_add_b_k<<<dim3(79, 7), 256, 0, stream>>>(ROWPTR7, CURSOR7, BLKSUM7, cp);
    fill_b_k<<<egrid7, 256, 0, stream>>>(edges, CURSOR7, ESRC7, cp);

    for (int k = 0; k < 7; ++k) {
      const HopDesc hd = hops[k];
      const u16* hsrc = (hd.src_tf >= 0) ? (TF + (size_t)OFFS_H[hd.src_tf] * 128) : H;
      const int n = hd.n_dst;

      // mean-aggregate into bf16
      gather_agg_k<<<dim3((n * 16 + 255) / 256), 256, 0, stream>>>(
          hsrc, ROWPTR7 + k * RP_STRIDE, ESRC7 + (size_t)k * E_EDGES, AGGB, n);

      // h = agg @ (diag(comp)*W_gcn[g]) + b_gcn[g]
      gemm_k<128, 128, ACT_NONE, 0, false, false><<<ggrid(n), 256, 0, stream>>>(
          AGGB, 128, BT_HOP + (size_t)hd.et * 128 * 128, b_gcn + (size_t)GRP_H[hd.et] * 128,
          H, 128, n, nullptr, nullptr);
      if (hd.out_p >= 0)
        permgather_k<<<dim3((nL * 16 + 255) / 256), 256, 0, stream>>>(
            H, perm, OUTS + (size_t)hd.out_p * 80000 * 128, nL);
    }

    // fusion
    if (NP != nL)                                  // zero K-pad columns for gram
      hipMemsetAsync(ZT, 0, (size_t)192 * NP * 2, stream);
    for (int p = 0; p < 3; ++p)
      gemm_k<128, 64, ACT_TANH, 0, false, false, true><<<ggrid(nL), 256, 0, stream>>>(
          OUTS + (size_t)p * 80000 * 128, 128, FCT + (size_t)(L * 3 + p) * 64 * 128, nullptr,
          Z + p * 64, 192, nL, nullptr, nullptr,
          ZT + (size_t)p * 64 * NP, NP);
    gram_k<<<dim3(GRAM_NKB, 3), 256, 0, stream>>>(ZT, NP, G + (size_t)L * 3 * 4096);
    float* fused = out + (L ? 6400000 : 0);
    gemm_k<192, 128, ACT_NONE, 0, true, false><<<ggrid(nL), 256, 0, stream>>>(
        Z, 192, VT + (size_t)L * 128 * 192, nullptr, fused, 128, nL, nullptr, nullptr);
    gemm_k<128, 192, ACT_NONE, 1, false, false><<<ggrid(nL), 256, 0, stream>>>(
        fused, 128, VRT + (size_t)L * 192 * 128, nullptr, ZREC, 192, nL, nullptr, nullptr);
    for (int p = 0; p < 3; ++p)
      gemm_k<64, 128, ACT_NONE, 0, false, true><<<ggrid(nL), 256, 0, stream>>>(
          ZREC + p * 64, 192, FCRT + (size_t)(L * 3 + p) * 128 * 64, nullptr,
          nullptr, 128, nL, OUTS + (size_t)p * 80000 * 128, RE + L);
  }

  loss_k<<<1, 256, 0, stream>>>(G, RE, out + 16640000);
}

// Round 6
// 1640.056 us; speedup vs baseline: 1.6112x; 1.1943x over previous
//
#include <hip/hip_runtime.h>

typedef unsigned short u16;
typedef unsigned int   u32;

#define ACT_NONE 0
#define ACT_RELU 1
#define ACT_TANH 2

#define E_EDGES 500000
#define RP_STRIDE 80004   // per-hop stride for cnt/rowptr (ints, 16B-aligned)

using s8vec = __attribute__((ext_vector_type(8))) short;   // 8 bf16 (4 VGPRs) MFMA A/B frag
using f4vec = __attribute__((ext_vector_type(4))) float;   // MFMA C/D frag

__device__ __forceinline__ float bf2f(u16 u) {
  union { u32 b; float f; } v; v.b = ((u32)u) << 16; return v.f;
}
__device__ __forceinline__ u16 f2bf(float x) {
  union { float f; u32 b; } v; v.f = x;
  u32 r = v.b + 0x7fffu + ((v.b >> 16) & 1u);   // round-to-nearest-even
  return (u16)(r >> 16);
}

// ---------------------------------------------------------------------------
// transpose + cast f32->bf16 (+ optional per-row f32 scale): in[R][C] -> out[C][R]
__global__ __launch_bounds__(256) void transpose_k(
    const float* __restrict__ in, u16* __restrict__ o, int R, int C,
    const float* __restrict__ scale) {
  int i = blockIdx.x * 256 + threadIdx.x;
  if (i >= R * C) return;
  int r = i / C, c = i % C;
  float v = in[i];
  if (scale) v *= scale[r];
  o[(size_t)c * R + r] = f2bf(v);
}

// ---------------------------------------------------------------------------
// inverse permutation: iperm[perm[i]] = i
__global__ __launch_bounds__(256) void iperm_k(
    const int* __restrict__ perm, int* __restrict__ iperm, int n) {
  int i = blockIdx.x * 256 + threadIdx.x;
  if (i < n) iperm[perm[i]] = i;
}

// ---------------------------------------------------------------------------
// Batched CSR build over all 14 hops (user 0-6, item 7-13); blockIdx.y = hop
struct Csr14 { int n[14]; int nblk[14]; };

// count + per-edge rank in ONE atomic
__global__ __launch_bounds__(256) void count14_k(
    const int* __restrict__ eu, const int* __restrict__ ei,
    int* __restrict__ cnt, int* __restrict__ rank) {
  int hop = blockIdx.y;
  int e = blockIdx.x * 256 + threadIdx.x;
  if (e >= E_EDGES) return;
  const int* edges = (hop < 7) ? eu : ei;
  int h7 = (hop < 7) ? hop : hop - 7;
  int d = edges[(size_t)(h7 * 2 + 1) * E_EDGES + e];
  rank[(size_t)hop * E_EDGES + e] = atomicAdd(&cnt[hop * RP_STRIDE + d], 1);
}

// per-block exclusive scan of 1024 elements (256 thr x 4), writes block total
__global__ __launch_bounds__(256) void scan_block14_k(
    const int* __restrict__ cntb, int* __restrict__ rowptrb,
    int* __restrict__ blksumb, Csr14 cp) {
  __shared__ int lds[256];
  const int hop = blockIdx.y;
  const int n = cp.n[hop];
  if (blockIdx.x * 1024 >= n) return;
  const int* in = cntb + hop * RP_STRIDE;
  int* out = rowptrb + hop * RP_STRIDE;
  const int t = threadIdx.x;
  const int idx = blockIdx.x * 1024 + t * 4;
  int v0 = 0, v1 = 0, v2 = 0, v3 = 0;
  if (idx + 3 < n) {
    int4 v = *(const int4*)(in + idx);
    v0 = v.x; v1 = v.y; v2 = v.z; v3 = v.w;
  } else {
    if (idx + 0 < n) v0 = in[idx + 0];
    if (idx + 1 < n) v1 = in[idx + 1];
    if (idx + 2 < n) v2 = in[idx + 2];
    if (idx + 3 < n) v3 = in[idx + 3];
  }
  int s0 = v0, s1 = s0 + v1, s2 = s1 + v2, s3 = s2 + v3;  // inclusive in-thread
  lds[t] = s3;
  __syncthreads();
  for (int off = 1; off < 256; off <<= 1) {               // Hillis-Steele
    int val = (t >= off) ? lds[t - off] : 0;
    __syncthreads();
    lds[t] += val;
    __syncthreads();
  }
  int excl = t ? lds[t - 1] : 0;
  if (idx + 3 < n) {
    int4 o = {excl, excl + s0, excl + s1, excl + s2};
    *(int4*)(out + idx) = o;
  } else {
    if (idx + 0 < n) out[idx + 0] = excl;
    if (idx + 1 < n) out[idx + 1] = excl + s0;
    if (idx + 2 < n) out[idx + 2] = excl + s1;
    if (idx + 3 < n) out[idx + 3] = excl + s2;
  }
  if (t == 255) blksumb[hop * 128 + blockIdx.x] = lds[255];
}

__global__ void scan_small14_k(int* __restrict__ blksumb, Csr14 cp) {
  int hop = blockIdx.x;
  if (threadIdx.x == 0) {
    int* b = blksumb + hop * 128;
    int s = 0;
    int nb = cp.nblk[hop];
    for (int i = 0; i < nb; ++i) { int t = b[i]; b[i] = s; s += t; }
  }
}

__global__ __launch_bounds__(256) void scan_add14_k(
    int* __restrict__ rowptrb, const int* __restrict__ blksumb, Csr14 cp) {
  const int hop = blockIdx.y;
  const int n = cp.n[hop];
  if (blockIdx.x * 1024 >= n) return;
  int* rowptr = rowptrb + hop * RP_STRIDE;
  const int t = threadIdx.x;
  const int idx = blockIdx.x * 1024 + t * 4;
  int boff = blksumb[hop * 128 + blockIdx.x];
#pragma unroll
  for (int j = 0; j < 4; ++j)
    if (idx + j < n) rowptr[idx + j] += boff;
  if (blockIdx.x == 0 && t == 0) rowptr[n] = E_EDGES;
}

// atomic-free fill: pos = rowptr[d] + rank[e]
__global__ __launch_bounds__(256) void fill14_k(
    const int* __restrict__ eu, const int* __restrict__ ei,
    const int* __restrict__ rowptrb, const int* __restrict__ rank,
    int* __restrict__ esrcb) {
  int hop = blockIdx.y;
  int e = blockIdx.x * 256 + threadIdx.x;
  if (e >= E_EDGES) return;
  const int* edges = (hop < 7) ? eu : ei;
  int h7 = (hop < 7) ? hop : hop - 7;
  int s = edges[(size_t)(h7 * 2) * E_EDGES + e];
  int d = edges[(size_t)(h7 * 2 + 1) * E_EDGES + e];
  int pos = rowptrb[hop * RP_STRIDE + d] + rank[(size_t)hop * E_EDGES + e];
  esrcb[(size_t)hop * E_EDGES + pos] = s;
}

// ---------------------------------------------------------------------------
// gather aggregation: aggb[d] = mean_{e: dst=d} h[src[e]]  (bf16 in/out, f32 acc)
// 16 lanes per dst row, 8 cols each
__device__ __forceinline__ void acc8(float* acc, uint4 v) {
  union { u32 b; float f; } cv;
  cv.b = v.x << 16;         acc[0] += cv.f;
  cv.b = v.x & 0xffff0000u; acc[1] += cv.f;
  cv.b = v.y << 16;         acc[2] += cv.f;
  cv.b = v.y & 0xffff0000u; acc[3] += cv.f;
  cv.b = v.z << 16;         acc[4] += cv.f;
  cv.b = v.z & 0xffff0000u; acc[5] += cv.f;
  cv.b = v.w << 16;         acc[6] += cv.f;
  cv.b = v.w & 0xffff0000u; acc[7] += cv.f;
}

__global__ __launch_bounds__(256) void gather_agg_k(
    const u16* __restrict__ h, const int* __restrict__ rowptr,
    const int* __restrict__ esrc, u16* __restrict__ aggb, int n) {
  int tid = blockIdx.x * 256 + threadIdx.x;
  int d = tid >> 4;
  if (d >= n) return;
  int part = tid & 15;
  int s0 = rowptr[d], s1 = rowptr[d + 1];
  float acc[8] = {0.f, 0.f, 0.f, 0.f, 0.f, 0.f, 0.f, 0.f};
  int i = s0;
  for (; i + 1 < s1; i += 2) {                  // 2-deep for outstanding loads
    int sa = esrc[i], sb = esrc[i + 1];
    uint4 va = *(const uint4*)(h + (size_t)sa * 128 + part * 8);
    uint4 vb = *(const uint4*)(h + (size_t)sb * 128 + part * 8);
    acc8(acc, va);
    acc8(acc, vb);
  }
  if (i < s1) {
    int sa = esrc[i];
    acc8(acc, *(const uint4*)(h + (size_t)sa * 128 + part * 8));
  }
  float rs = 1.0f / fmaxf((float)(s1 - s0), 1.0f);
  u16 o[8];
#pragma unroll
  for (int j = 0; j < 8; ++j) o[j] = f2bf(acc[j] * rs);
  *(uint4*)(aggb + (size_t)d * 128 + part * 8) = *(const uint4*)o;
}

// ---------------------------------------------------------------------------
// MFMA GEMM: C[M][N] = act(A[M][K] @ B[K][N] + bias)
//  - Bt is B transposed [N][K] bf16 (global), staged in LDS with XOR-granule swizzle
//  - AMODE: 0 = bf16 A, 1 = f32 A
//  - CF32:  write f32 (else bf16)
//  - CTR:   additionally write C transposed (bf16) to Ct[col][row], ld=ldCt
//  - SQDIFF: don't store; accumulate sum((v - target)^2) into lossAcc
//  - PERMOUT: write rows permuted: C[iperm[r]][col]
// block = 256 threads = 4 waves, 64 rows/block, wave w owns rows w*16..w*16+15
template <int K, int N, int ACT, int AMODE, bool CF32, bool SQDIFF,
          bool CTR = false, bool PERMOUT = false>
__global__ __launch_bounds__(256) void gemm_k(
    const void* __restrict__ Av, int ldA,
    const u16* __restrict__ Bt, const float* __restrict__ bias,
    void* __restrict__ Cv, int ldC, int M,
    const u16* __restrict__ target, float* __restrict__ lossAcc,
    u16* __restrict__ Ct = nullptr, int ldCt = 0,
    const int* __restrict__ iperm = nullptr) {
  static_assert(K % 32 == 0 && N % 16 == 0, "");
  __shared__ u16 bts[N * K];
  __shared__ float red[4];

  const int tid = threadIdx.x;
  // stage Bt -> LDS, swizzling 8-elem (16B) granules: gs = (g&~7) | ((g^n)&7)
  for (int i = tid; i < N * (K / 8); i += 256) {
    int n = i / (K / 8);
    int g = i % (K / 8);
    int gs = (g & ~7) | ((g ^ n) & 7);
    *(uint4*)(&bts[n * K + gs * 8]) = *(const uint4*)(Bt + (size_t)n * K + g * 8);
  }
  __syncthreads();

  const int wave = tid >> 6;
  const int lane = tid & 63;
  const int kgrp = lane >> 4;              // 0..3
  const int rbase = blockIdx.x * 64 + wave * 16;
  const int rowA = rbase + (lane & 15);
  const bool av = rowA < M;

  // A fragments for the whole K extent, in registers
  s8vec afr[K / 32];
  if constexpr (AMODE == 1) {
    const float* arow = (const float*)Av + (size_t)rowA * ldA;
#pragma unroll
    for (int kt = 0; kt < K / 32; ++kt) {
      s8vec fr = {0, 0, 0, 0, 0, 0, 0, 0};
      if (av) {
        const float* p = arow + kt * 32 + kgrp * 8;
        float4 f0 = *(const float4*)(p);
        float4 f1 = *(const float4*)(p + 4);
        fr[0] = (short)f2bf(f0.x); fr[1] = (short)f2bf(f0.y);
        fr[2] = (short)f2bf(f0.z); fr[3] = (short)f2bf(f0.w);
        fr[4] = (short)f2bf(f1.x); fr[5] = (short)f2bf(f1.y);
        fr[6] = (short)f2bf(f1.z); fr[7] = (short)f2bf(f1.w);
      }
      afr[kt] = fr;
    }
  } else {
    const u16* arow = (const u16*)Av + (size_t)rowA * ldA;
#pragma unroll
    for (int kt = 0; kt < K / 32; ++kt) {
      s8vec fr = {0, 0, 0, 0, 0, 0, 0, 0};
      if (av) fr = *(const s8vec*)(arow + kt * 32 + kgrp * 8);
      afr[kt] = fr;
    }
  }

  float sqsum = 0.0f;
#pragma unroll
  for (int t = 0; t < N / 16; ++t) {
    f4vec acc = {0.f, 0.f, 0.f, 0.f};
    const int bn = t * 16 + (lane & 15);
#pragma unroll
    for (int kt = 0; kt < K / 32; ++kt) {
      int g = kt * 4 + kgrp;
      int gs = (g & ~7) | ((g ^ bn) & 7);
      s8vec bfr = *(const s8vec*)(&bts[bn * K + gs * 8]);
      acc = __builtin_amdgcn_mfma_f32_16x16x32_bf16(afr[kt], bfr, acc, 0, 0, 0);
    }
    const int col = t * 16 + (lane & 15);
    float bb = bias ? bias[col] : 0.0f;
#pragma unroll
    for (int j = 0; j < 4; ++j) {
      int r = rbase + kgrp * 4 + j;        // C/D: col=lane&15, row=(lane>>4)*4+j
      if (r < M) {
        float v = acc[j] + bb;
        if constexpr (ACT == ACT_RELU) v = fmaxf(v, 0.0f);
        if constexpr (ACT == ACT_TANH) v = tanhf(v);
        if constexpr (SQDIFF) {
          float dd = v - bf2f(target[(size_t)r * 128 + col]);
          sqsum += dd * dd;
        } else if constexpr (CF32) {
          ((float*)Cv)[(size_t)r * ldC + col] = v;
        } else {
          int ro = r;
          if constexpr (PERMOUT) ro = iperm[r];
          ((u16*)Cv)[(size_t)ro * ldC + col] = f2bf(v);
        }
        if constexpr (CTR) {
          Ct[(size_t)col * ldCt + r] = f2bf(v);
        }
      }
    }
  }

  if constexpr (SQDIFF) {
#pragma unroll
    for (int off = 32; off > 0; off >>= 1) sqsum += __shfl_down(sqsum, off);
    if (lane == 0) red[wave] = sqsum;
    __syncthreads();
    if (tid == 0) atomicAdd(lossAcc, red[0] + red[1] + red[2] + red[3]);
  }
}

// ---------------------------------------------------------------------------
// Gram via MFMA: for pair (p,q), G_pair[m][n] += sum_r ZT[p*64+m][r]*ZT[q*64+n][r]
// grid = (NKB, 3); block = 4 waves; wave w owns G rows [w*16, w*16+16)
#define GRAM_NKB 40
__global__ __launch_bounds__(256) void gram_k(
    const u16* __restrict__ zt, int NP, float* __restrict__ G3) {
  const int pair = blockIdx.y;
  const int p = (pair == 2) ? 1 : 0;
  const int q = (pair == 0) ? 1 : 2;
  const int wave = threadIdx.x >> 6;
  const int lane = threadIdx.x & 63;
  const int kgrp = lane >> 4, lid = lane & 15;

  const int KC = (((NP + GRAM_NKB - 1) / GRAM_NKB) + 31) & ~31;
  const int kbeg = blockIdx.x * KC;
  const int kend = min(NP, kbeg + KC);

  const u16* arow = zt + (size_t)(p * 64 + wave * 16 + lid) * NP;
  const u16* brow0 = zt + (size_t)(q * 64 + 0 * 16 + lid) * NP;
  const u16* brow1 = zt + (size_t)(q * 64 + 1 * 16 + lid) * NP;
  const u16* brow2 = zt + (size_t)(q * 64 + 2 * 16 + lid) * NP;
  const u16* brow3 = zt + (size_t)(q * 64 + 3 * 16 + lid) * NP;

  f4vec acc0 = {0.f, 0.f, 0.f, 0.f};
  f4vec acc1 = {0.f, 0.f, 0.f, 0.f};
  f4vec acc2 = {0.f, 0.f, 0.f, 0.f};
  f4vec acc3 = {0.f, 0.f, 0.f, 0.f};

  for (int k0 = kbeg; k0 < kend; k0 += 32) {
    const int ko = k0 + kgrp * 8;
    s8vec af = *(const s8vec*)(arow + ko);
    s8vec b0 = *(const s8vec*)(brow0 + ko);
    s8vec b1 = *(const s8vec*)(brow1 + ko);
    s8vec b2 = *(const s8vec*)(brow2 + ko);
    s8vec b3 = *(const s8vec*)(brow3 + ko);
    acc0 = __builtin_amdgcn_mfma_f32_16x16x32_bf16(af, b0, acc0, 0, 0, 0);
    acc1 = __builtin_amdgcn_mfma_f32_16x16x32_bf16(af, b1, acc1, 0, 0, 0);
    acc2 = __builtin_amdgcn_mfma_f32_16x16x32_bf16(af, b2, acc2, 0, 0, 0);
    acc3 = __builtin_amdgcn_mfma_f32_16x16x32_bf16(af, b3, acc3, 0, 0, 0);
  }

  float* g = G3 + (size_t)pair * 4096;
  const int mrow = wave * 16 + kgrp * 4;
#pragma unroll
  for (int j = 0; j < 4; ++j) {
    atomicAdd(&g[(mrow + j) * 64 + 0 * 16 + lid], acc0[j]);
    atomicAdd(&g[(mrow + j) * 64 + 1 * 16 + lid], acc1[j]);
    atomicAdd(&g[(mrow + j) * 64 + 2 * 16 + lid], acc2[j]);
    atomicAdd(&g[(mrow + j) * 64 + 3 * 16 + lid], acc3[j]);
  }
}

// ---------------------------------------------------------------------------
__global__ __launch_bounds__(256) void loss_k(
    const float* __restrict__ G, const float* __restrict__ RE,
    float* __restrict__ out) {
  float s = 0.f;
  for (int i = threadIdx.x; i < 2 * 3 * 4096; i += 256) { float g = G[i]; s += g * g; }
#pragma unroll
  for (int off = 32; off > 0; off >>= 1) s += __shfl_down(s, off);
  __shared__ float red[4];
  int wave = threadIdx.x >> 6, lane = threadIdx.x & 63;
  if (lane == 0) red[wave] = s;
  __syncthreads();
  if (threadIdx.x == 0) {
    float orth = (red[0] + red[1] + red[2] + red[3]) / 4096.0f;
    float loss = orth + RE[0] / (50000.0f * 128.0f) + RE[1] / (80000.0f * 128.0f);
    out[0] = loss;
  }
}

// ---------------------------------------------------------------------------
struct HopDesc { int et; int src_tf; int n_dst; int out_p; };  // src_tf: -1 = H buffer

static const int COUNTS_H[3] = {50000, 80000, 10000};
static const int OFFS_H[3]   = {0, 50000, 130000};
static const int GRP_H[5]    = {2, 1, 1, 2, 1};                // GCN_GROUP

static const HopDesc HOPS_U[7] = {
  {0, 0, 80000, -1}, {1, -1, 50000, 0},
  {0, 0, 80000, -1}, {2, -1, 10000, -1}, {3, -1, 80000, -1}, {1, -1, 50000, 1},
  {4, 0, 50000, 2}};
static const HopDesc HOPS_I[7] = {
  {1, 1, 50000, -1}, {0, -1, 80000, 0},
  {2, 1, 10000, -1}, {3, -1, 80000, 1},
  {1, 1, 50000, -1}, {4, -1, 50000, -1}, {0, -1, 80000, 2}};

extern "C" void kernel_launch(void* const* d_in, const int* in_sizes, int n_in,
                              void* d_out, int out_size, void* d_ws, size_t ws_size,
                              hipStream_t stream) {
  (void)in_sizes; (void)n_in; (void)out_size; (void)ws_size;

  const float* features = (const float*)d_in[0];
  const int* e_user   = (const int*)d_in[1];
  const int* e_item   = (const int*)d_in[2];
  const int* perm_u   = (const int*)d_in[3];
  const int* perm_i   = (const int*)d_in[4];
  const float* W_type = (const float*)d_in[5];
  const float* b_type = (const float*)d_in[6];
  const float* comp   = (const float*)d_in[7];
  const float* W_gcn  = (const float*)d_in[8];
  const float* b_gcn  = (const float*)d_in[9];
  const float* fc[2]  = {(const float*)d_in[10], (const float*)d_in[14]};
  const float* fcr[2] = {(const float*)d_in[11], (const float*)d_in[15]};
  const float* V[2]   = {(const float*)d_in[12], (const float*)d_in[16]};
  const float* Vr[2]  = {(const float*)d_in[13], (const float*)d_in[17]};
  float* out = (float*)d_out;

  char* base = (char*)d_ws;
  size_t off = 0;
  auto alloc = [&](size_t b) -> void* {
    void* p = base + off;
    off = (off + b + 255) & ~(size_t)255;
    return p;
  };
  u16*  TF   = (u16*) alloc(140000ull * 128 * 2);
  u16*  H    = (u16*) alloc(80000ull * 128 * 2);
  u16*  AGGB = (u16*) alloc(80000ull * 128 * 2);
  u16*  OUTS = (u16*) alloc(3ull * 80000 * 128 * 2);
  u16*  Z    = (u16*) alloc(80000ull * 192 * 2);
  u16*  ZREC = (u16*) alloc(80000ull * 192 * 2);
  u16*  ZT   = (u16*) alloc(192ull * 80032 * 2);   // also aliased as RANK14 early
  float* G   = (float*)alloc((2 * 3 * 4096 + 2) * 4);
  float* RE  = G + 2 * 3 * 4096;
  int* CNT14    = (int*)alloc(14ull * RP_STRIDE * 4);
  int* ROWPTR14 = (int*)alloc(14ull * RP_STRIDE * 4);
  int* ESRC14   = (int*)alloc(14ull * E_EDGES * 4);
  int* BLKSUM14 = (int*)alloc(14ull * 128 * 4);
  int* IPERM    = (int*)alloc(130000ull * 4);       // [user 50k][item 80k]
  u16* WT_TYPE = (u16*)alloc(3ull * 128 * 256 * 2);
  u16* BT_HOP  = (u16*)alloc(5ull * 128 * 128 * 2);
  u16* FCT     = (u16*)alloc(6ull * 64 * 128 * 2);
  u16* VT      = (u16*)alloc(2ull * 128 * 192 * 2);
  u16* VRT     = (u16*)alloc(2ull * 192 * 128 * 2);
  u16* FCRT    = (u16*)alloc(6ull * 128 * 64 * 2);
  int* RANK14 = (int*)ZT;   // 14*500000*4 = 28 MB <= ZT's 30.7 MB; dead before fusion

  auto tgrid = [](int n) { return dim3((unsigned)((n + 255) / 256)); };
  auto ggrid = [](int M) { return dim3((unsigned)((M + 63) / 64)); };
  const dim3 egrid14((E_EDGES + 255) / 256, 14);

  // ---- CSR build for all 14 hops (independent of everything else) --------
  Csr14 cp;
  for (int k = 0; k < 7; ++k) {
    cp.n[k] = HOPS_U[k].n_dst;      cp.nblk[k] = (cp.n[k] + 1023) / 1024;
    cp.n[k + 7] = HOPS_I[k].n_dst;  cp.nblk[k + 7] = (cp.n[k + 7] + 1023) / 1024;
  }
  hipMemsetAsync(CNT14, 0, 14ull * RP_STRIDE * 4, stream);
  count14_k<<<egrid14, 256, 0, stream>>>(e_user, e_item, CNT14, RANK14);
  scan_block14_k<<<dim3(79, 14), 256, 0, stream>>>(CNT14, ROWPTR14, BLKSUM14, cp);
  scan_small14_k<<<dim3(14), 64, 0, stream>>>(BLKSUM14, cp);
  scan_add14_k<<<dim3(79, 14), 256, 0, stream>>>(ROWPTR14, BLKSUM14, cp);
  fill14_k<<<egrid14, 256, 0, stream>>>(e_user, e_item, ROWPTR14, RANK14, ESRC14);

  // ---- inverse perms ------------------------------------------------------
  iperm_k<<<tgrid(50000), 256, 0, stream>>>(perm_u, IPERM, 50000);
  iperm_k<<<tgrid(80000), 256, 0, stream>>>(perm_i, IPERM + 50000, 80000);

  // ---- weight prep: transposed (and comp-folded) bf16 copies -------------
  for (int t = 0; t < 3; ++t)
    transpose_k<<<tgrid(256 * 128), 256, 0, stream>>>(
        W_type + (size_t)t * 256 * 128, WT_TYPE + (size_t)t * 128 * 256, 256, 128, nullptr);
  for (int et = 0; et < 5; ++et)
    transpose_k<<<tgrid(128 * 128), 256, 0, stream>>>(
        W_gcn + (size_t)GRP_H[et] * 128 * 128, BT_HOP + (size_t)et * 128 * 128, 128, 128,
        comp + (size_t)et * 128);
  for (int L = 0; L < 2; ++L) {
    for (int p = 0; p < 3; ++p) {
      transpose_k<<<tgrid(128 * 64), 256, 0, stream>>>(
          fc[L] + (size_t)p * 128 * 64, FCT + (size_t)(L * 3 + p) * 64 * 128, 128, 64, nullptr);
      transpose_k<<<tgrid(64 * 128), 256, 0, stream>>>(
          fcr[L] + (size_t)p * 64 * 128, FCRT + (size_t)(L * 3 + p) * 128 * 64, 64, 128, nullptr);
    }
    transpose_k<<<tgrid(192 * 128), 256, 0, stream>>>(V[L], VT + (size_t)L * 128 * 192, 192, 128, nullptr);
    transpose_k<<<tgrid(128 * 192), 256, 0, stream>>>(Vr[L], VRT + (size_t)L * 192 * 128, 128, 192, nullptr);
  }
  hipMemsetAsync(G, 0, (2 * 3 * 4096 + 2) * 4, stream);

  // ---- NodeTransform: TF[t] = relu(features_t @ W_type[t] + b_type[t]) ---
  for (int t = 0; t < 3; ++t)
    gemm_k<256, 128, ACT_RELU, 1, false, false><<<ggrid(COUNTS_H[t]), 256, 0, stream>>>(
        features + (size_t)OFFS_H[t] * 256, 256, WT_TYPE + (size_t)t * 128 * 256,
        b_type + (size_t)t * 128, TF + (size_t)OFFS_H[t] * 128, 128, COUNTS_H[t],
        nullptr, nullptr);

  // ---- two layers ----------------------------------------------------------
  for (int L = 0; L < 2; ++L) {
    const HopDesc* hops = L ? HOPS_I : HOPS_U;
    const int  nL    = L ? 80000 : 50000;
    const int  NP    = (nL + 31) & ~31;           // K-padded node count for ZT
    const int* ipermL = IPERM + (L ? 50000 : 0);
    const int  hbase  = L ? 7 : 0;

    for (int k = 0; k < 7; ++k) {
      const HopDesc hd = hops[k];
      const u16* hsrc = (hd.src_tf >= 0) ? (TF + (size_t)OFFS_H[hd.src_tf] * 128) : H;
      const int n = hd.n_dst;
      const int* rowptr = ROWPTR14 + (hbase + k) * RP_STRIDE;
      const int* esrc   = ESRC14 + (size_t)(hbase + k) * E_EDGES;

      // mean-aggregate into bf16
      gather_agg_k<<<dim3((n * 16 + 255) / 256), 256, 0, stream>>>(
          hsrc, rowptr, esrc, AGGB, n);

      // h = agg @ (diag(comp)*W_gcn[g]) + b_gcn[g]
      if (hd.out_p >= 0) {
        // final hop of a metapath: write straight into OUTS, permuted
        gemm_k<128, 128, ACT_NONE, 0, false, false, false, true>
            <<<ggrid(n), 256, 0, stream>>>(
            AGGB, 128, BT_HOP + (size_t)hd.et * 128 * 128, b_gcn + (size_t)GRP_H[hd.et] * 128,
            OUTS + (size_t)hd.out_p * 80000 * 128, 128, n,
            nullptr, nullptr, nullptr, 0, ipermL);
      } else {
        gemm_k<128, 128, ACT_NONE, 0, false, false><<<ggrid(n), 256, 0, stream>>>(
            AGGB, 128, BT_HOP + (size_t)hd.et * 128 * 128, b_gcn + (size_t)GRP_H[hd.et] * 128,
            H, 128, n, nullptr, nullptr);
      }
    }

    // fusion
    if (NP != nL)                                  // zero K-pad columns for gram
      hipMemsetAsync(ZT, 0, (size_t)192 * NP * 2, stream);
    for (int p = 0; p < 3; ++p)
      gemm_k<128, 64, ACT_TANH, 0, false, false, true><<<ggrid(nL), 256, 0, stream>>>(
          OUTS + (size_t)p * 80000 * 128, 128, FCT + (size_t)(L * 3 + p) * 64 * 128, nullptr,
          Z + p * 64, 192, nL, nullptr, nullptr,
          ZT + (size_t)p * 64 * NP, NP);
    gram_k<<<dim3(GRAM_NKB, 3), 256, 0, stream>>>(ZT, NP, G + (size_t)L * 3 * 4096);
    float* fused = out + (L ? 6400000 : 0);
    gemm_k<192, 128, ACT_NONE, 0, true, false><<<ggrid(nL), 256, 0, stream>>>(
        Z, 192, VT + (size_t)L * 128 * 192, nullptr, fused, 128, nL, nullptr, nullptr);
    gemm_k<128, 192, ACT_NONE, 1, false, false><<<ggrid(nL), 256, 0, stream>>>(
        fused, 128, VRT + (size_t)L * 192 * 128, nullptr, ZREC, 192, nL, nullptr, nullptr);
    for (int p = 0; p < 3; ++p)
      gemm_k<64, 128, ACT_NONE, 0, false, true><<<ggrid(nL), 256, 0, stream>>>(
          ZREC + p * 64, 192, FCRT + (size_t)(L * 3 + p) * 128 * 64, nullptr,
          nullptr, 128, nL, OUTS + (size_t)p * 80000 * 128, RE + L);
  }

  loss_k<<<1, 256, 0, stream>>>(G, RE, out + 16640000);
}